// Round 1
// baseline (2561.134 us; speedup 1.0000x reference)
//
#include <hip/hip_runtime.h>

#define QN 150
#define CN 512
#define HWN 441
#define WAYN 5
#define SHOTN 5
#define NSAMP 2205   // SHOT*HW

// ---------------- per-(way,channel) mean over 2205 samples ----------------
__global__ void wmean_kernel(const float* __restrict__ x2, float* __restrict__ wmean) {
    int wc = blockIdx.x;            // w*512 + c
    int w = wc >> 9, c = wc & 511;
    int lane = threadIdx.x;         // 64
    float s = 0.f;
    for (int sh = 0; sh < SHOTN; ++sh) {
        const float* p = x2 + ((size_t)((w * SHOTN + sh) * CN + c)) * HWN;
        for (int i = lane; i < HWN; i += 64) s += p[i];
    }
    #pragma unroll
    for (int off = 32; off > 0; off >>= 1) s += __shfl_down(s, off);
    if (lane == 0) wmean[wc] = s * (1.0f / NSAMP);
}

// ---------------- per-(query,channel) mean over 441 positions ----------------
__global__ void qmean_kernel(const float* __restrict__ x1, float* __restrict__ qmean) {
    int qc = blockIdx.x;            // q*512 + c
    const float* p = x1 + (size_t)qc * HWN;
    int lane = threadIdx.x;
    float s = 0.f;
    for (int i = lane; i < HWN; i += 64) s += p[i];
    #pragma unroll
    for (int off = 32; off > 0; off >>= 1) s += __shfl_down(s, off);
    if (lane == 0) qmean[qc] = s * (1.0f / HWN);
}

// ---------------- covariance: cov[w] = (X X^T - n m m^T)/(n-1) ----------------
// X = 512 x 2205 (k = shot*441 + pos).  64x64 (c,d) tile per block, 4x4 per thread.
#define COV_KC 32
__global__ __launch_bounds__(256) void cov_kernel(const float* __restrict__ x2,
                                                  const float* __restrict__ wmean,
                                                  float* __restrict__ cov) {
    __shared__ float Xc[COV_KC][68];   // [k][c], padded
    __shared__ float Xd[COV_KC][68];
    int w  = blockIdx.z;
    int c0 = blockIdx.y * 64;
    int d0 = blockIdx.x * 64;
    int tx = threadIdx.x, ty = threadIdx.y;   // 16x16
    int tid = ty * 16 + tx;
    int col  = tid & 31;     // k within chunk
    int row8 = tid >> 5;     // 0..7
    float acc[4][4] = {};
    const float* xw = x2 + (size_t)w * SHOTN * CN * HWN;

    for (int k0 = 0; k0 < NSAMP; k0 += COV_KC) {
        int k = k0 + col;
        bool ok = (k < NSAMP);
        int s   = k / HWN;
        int pos = k - s * HWN;
        #pragma unroll
        for (int r = 0; r < 8; ++r) {
            int rc = row8 + r * 8;
            Xc[col][rc] = ok ? xw[((size_t)(s * CN + (c0 + rc))) * HWN + pos] : 0.f;
            Xd[col][rc] = ok ? xw[((size_t)(s * CN + (d0 + rc))) * HWN + pos] : 0.f;
        }
        __syncthreads();
        #pragma unroll 4
        for (int kk = 0; kk < COV_KC; ++kk) {
            float4 a = *reinterpret_cast<const float4*>(&Xc[kk][ty * 4]);
            float4 b = *reinterpret_cast<const float4*>(&Xd[kk][tx * 4]);
            float av[4] = {a.x, a.y, a.z, a.w};
            float bv[4] = {b.x, b.y, b.z, b.w};
            #pragma unroll
            for (int i = 0; i < 4; ++i)
                #pragma unroll
                for (int j = 0; j < 4; ++j)
                    acc[i][j] += av[i] * bv[j];
        }
        __syncthreads();
    }
    const float inv = 1.0f / (NSAMP - 1);
    #pragma unroll
    for (int i = 0; i < 4; ++i) {
        int c = c0 + ty * 4 + i;
        float mc = wmean[w * CN + c];
        #pragma unroll
        for (int j = 0; j < 4; ++j) {
            int d = d0 + tx * 4 + j;
            float md = wmean[w * CN + d];
            cov[((size_t)w * CN + c) * CN + d] = (acc[i][j] - (float)NSAMP * mc * md) * inv;
        }
    }
}

// ---------------- scores init to conv_b ----------------
__global__ void init_scores(float* __restrict__ scores, const float* __restrict__ conv_b) {
    int i = blockIdx.x * blockDim.x + threadIdx.x;
    if (i < QN * WAYN) scores[i] = conv_b[0];
}

// ---------------- main phase: sim = rowdot(Qc @ Cov, Qc); leaky; conv dot ----------------
// block = (i-tile of 32, w, q); 256 threads; thread owns 4 i x 16 d fp32 accum.
#define TI 32
#define KC 16
__global__ __launch_bounds__(256) void phaseB_kernel(const float* __restrict__ x1,
                                                     const float* __restrict__ qmean,
                                                     const float* __restrict__ cov,
                                                     const float* __restrict__ conv_w,
                                                     float* __restrict__ scores) {
    __shared__ float As[KC][TI];       // centered Q tile [k][i]
    __shared__ float Bs[KC][CN];       // cov tile [k][d]
    __shared__ float red[256][4];
    int i0 = blockIdx.x * TI;
    int w  = blockIdx.y;
    int q  = blockIdx.z;
    int tid = threadIdx.x;
    int it = tid & 7;        // i group (4 rows)
    int dt = tid >> 3;       // d group (16 cols)
    int dbase = dt * 16;
    const float* xq   = x1 + (size_t)q * CN * HWN;
    const float* qm   = qmean + q * CN;
    const float* covw = cov + (size_t)w * CN * CN;
    float acc[4][16] = {};

    int ai = tid & 31;              // i for A staging
    int ak = tid >> 5;              // 0..7
    int bd = (tid & 127) * 4;       // d for B staging (float4)
    int bk = tid >> 7;              // 0..1
    bool iok = (i0 + ai) < HWN;

    for (int c0 = 0; c0 < CN; c0 += KC) {
        #pragma unroll
        for (int r = 0; r < 2; ++r) {
            int k = ak + r * 8;
            int c = c0 + k;
            As[k][ai] = iok ? (xq[(size_t)c * HWN + i0 + ai] - qm[c]) : 0.f;
        }
        #pragma unroll
        for (int r = 0; r < 8; ++r) {
            int k = bk + r * 2;
            *reinterpret_cast<float4*>(&Bs[k][bd]) =
                *reinterpret_cast<const float4*>(&covw[(size_t)(c0 + k) * CN + bd]);
        }
        __syncthreads();
        #pragma unroll 2
        for (int kk = 0; kk < KC; ++kk) {
            float4 a = *reinterpret_cast<const float4*>(&As[kk][it * 4]);
            float av[4] = {a.x, a.y, a.z, a.w};
            float bv[16];
            #pragma unroll
            for (int j4 = 0; j4 < 4; ++j4) {
                float4 b = *reinterpret_cast<const float4*>(&Bs[kk][dbase + j4 * 4]);
                bv[j4 * 4 + 0] = b.x; bv[j4 * 4 + 1] = b.y;
                bv[j4 * 4 + 2] = b.z; bv[j4 * 4 + 3] = b.w;
            }
            #pragma unroll
            for (int i = 0; i < 4; ++i)
                #pragma unroll
                for (int j = 0; j < 16; ++j)
                    acc[i][j] += av[i] * bv[j];
        }
        __syncthreads();
    }

    // sim partials: multiply S by Qc[i][d] over this thread's 16 d's
    float part[4] = {0.f, 0.f, 0.f, 0.f};
    #pragma unroll
    for (int i = 0; i < 4; ++i) {
        int ii = i0 + it * 4 + i;
        if (ii < HWN) {
            float p = 0.f;
            #pragma unroll
            for (int j = 0; j < 16; ++j) {
                int d = dbase + j;
                float qv = xq[(size_t)d * HWN + ii] - qm[d];
                p += acc[i][j] * qv;
            }
            part[i] = p;
        }
    }
    #pragma unroll
    for (int i = 0; i < 4; ++i) red[tid][i] = part[i];
    __syncthreads();

    if (tid < 32) {
        int it2 = tid & 7, i2 = tid >> 3;
        float s = 0.f;
        for (int m = 0; m < 32; ++m) s += red[it2 + 8 * m][i2];
        int ii = i0 + it2 * 4 + i2;
        float contrib = 0.f;
        if (ii < HWN) {
            float v = (s >= 0.f) ? s : 0.2f * s;   // LeakyReLU(0.2)
            contrib = v * conv_w[ii];
        }
        #pragma unroll
        for (int off = 16; off > 0; off >>= 1) contrib += __shfl_down(contrib, off);
        if (tid == 0) atomicAdd(&scores[q * WAYN + w], contrib);
    }
}

extern "C" void kernel_launch(void* const* d_in, const int* in_sizes, int n_in,
                              void* d_out, int out_size, void* d_ws, size_t ws_size,
                              hipStream_t stream) {
    const float* x1     = (const float*)d_in[0];
    const float* x2     = (const float*)d_in[1];
    const float* conv_w = (const float*)d_in[2];
    const float* conv_b = (const float*)d_in[3];
    float* scores = (float*)d_out;

    float* wmean = (float*)d_ws;          // 2560 floats
    float* qmean = wmean + 2560;          // 76800 floats
    float* cov   = qmean + 76800;         // 5*512*512 floats (total ws use ~5.6 MB)

    wmean_kernel<<<WAYN * CN, 64, 0, stream>>>(x2, wmean);
    qmean_kernel<<<QN * CN, 64, 0, stream>>>(x1, qmean);
    cov_kernel<<<dim3(8, 8, WAYN), dim3(16, 16), 0, stream>>>(x2, wmean, cov);
    init_scores<<<3, 256, 0, stream>>>(scores, conv_b);
    phaseB_kernel<<<dim3((HWN + TI - 1) / TI, WAYN, QN), 256, 0, stream>>>(
        x1, qmean, cov, conv_w, scores);
}

// Round 3
// 711.983 us; speedup vs baseline: 3.5972x; 3.5972x over previous
//
#include <hip/hip_runtime.h>
#include <hip/hip_bf16.h>

#define QN 150
#define CN 512
#define HWN 441
#define WAYN 5
#define SHOTN 5
#define NSAMP 2205   // SHOT*HW
#define MPAD 512     // padded i-rows per query
#define MTOT (QN * MPAD)  // 76800 padded rows

typedef unsigned short u16;
typedef unsigned int u32;
typedef __attribute__((ext_vector_type(8))) short short8;
typedef __attribute__((ext_vector_type(4))) float f32x4;

__device__ __forceinline__ u16 f2b(float f) {
    return __builtin_bit_cast(u16, __float2bfloat16(f));
}
__device__ __forceinline__ float b2f(u16 h) {
    u32 u = ((u32)h) << 16;
    return __builtin_bit_cast(float, u);
}

__device__ __forceinline__ void gload16(const void* g, void* l) {
    __builtin_amdgcn_global_load_lds(
        (const __attribute__((address_space(1))) unsigned int*)g,
        (__attribute__((address_space(3))) unsigned int*)l, 16, 0, 0);
}

// ---------------- per-(way,channel) mean over 2205 samples ----------------
__global__ void wmean_kernel(const float* __restrict__ x2, float* __restrict__ wmean) {
    int wc = blockIdx.x;            // w*512 + c
    int w = wc >> 9, c = wc & 511;
    int lane = threadIdx.x;         // 64
    float s = 0.f;
    for (int sh = 0; sh < SHOTN; ++sh) {
        const float* p = x2 + ((size_t)((w * SHOTN + sh) * CN + c)) * HWN;
        for (int i = lane; i < HWN; i += 64) s += p[i];
    }
    #pragma unroll
    for (int off = 32; off > 0; off >>= 1) s += __shfl_down(s, off);
    if (lane == 0) wmean[wc] = s * (1.0f / NSAMP);
}

// ---------------- transpose+center x1 -> Abf[(q*512+i)][c] bf16, pad rows zero ----------------
// block = (c-tile 64, q); 256 threads
__global__ __launch_bounds__(256) void qtrans_kernel(const float* __restrict__ x1,
                                                     u16* __restrict__ Abf) {
    __shared__ u16 S[MPAD][72];     // [i][c_local], pad 72 (144B rows, 16B aligned)
    __shared__ float qm[64];
    int c0 = blockIdx.x * 64;
    int q  = blockIdx.y;
    int t = threadIdx.x;
    int lane = t & 63, cq = t >> 6;

    // load + per-c mean (over fp32 originals)
    for (int cc = cq; cc < 64; cc += 4) {
        int c = c0 + cc;
        const float* p = x1 + ((size_t)q * CN + c) * HWN;
        float s = 0.f;
        for (int ic = 0; ic < 8; ++ic) {
            int i = ic * 64 + lane;
            float v = (i < HWN) ? p[i] : 0.f;
            s += v;
            S[i][cc] = f2b(v);
        }
        #pragma unroll
        for (int off = 32; off > 0; off >>= 1) s += __shfl_down(s, off);
        if (lane == 0) qm[cc] = s * (1.0f / HWN);
    }
    __syncthreads();

    // centered transpose write: thread = (i-row, c-octet)
    int coct = t & 7;
    for (int p = 0; p < 16; ++p) {
        int il = p * 32 + (t >> 3);
        short8 v = *(const short8*)(&S[il][coct * 8]);
        bool valid = il < HWN;
        short8 o;
        #pragma unroll
        for (int j = 0; j < 8; ++j) {
            float f = valid ? (b2f((u16)v[j]) - qm[coct * 8 + j]) : 0.f;
            o[j] = (short)f2b(f);
        }
        *(short8*)(Abf + ((size_t)q * MPAD + il) * CN + c0 + coct * 8) = o;
    }
}

// ---------------- covariance (fp32 math, bf16 out): cov[w] = (X X^T - n m m^T)/(n-1) ----------------
#define COV_KC 32
__global__ __launch_bounds__(256) void cov_kernel(const float* __restrict__ x2,
                                                  const float* __restrict__ wmean,
                                                  u16* __restrict__ covb) {
    __shared__ float Xc[COV_KC][68];
    __shared__ float Xd[COV_KC][68];
    int w  = blockIdx.z;
    int c0 = blockIdx.y * 64;
    int d0 = blockIdx.x * 64;
    int tx = threadIdx.x, ty = threadIdx.y;
    int tid = ty * 16 + tx;
    int col  = tid & 31;
    int row8 = tid >> 5;
    float acc[4][4] = {};
    const float* xw = x2 + (size_t)w * SHOTN * CN * HWN;

    for (int k0 = 0; k0 < NSAMP; k0 += COV_KC) {
        int k = k0 + col;
        bool ok = (k < NSAMP);
        int s   = k / HWN;
        int pos = k - s * HWN;
        #pragma unroll
        for (int r = 0; r < 8; ++r) {
            int rc = row8 + r * 8;
            Xc[col][rc] = ok ? xw[((size_t)(s * CN + (c0 + rc))) * HWN + pos] : 0.f;
            Xd[col][rc] = ok ? xw[((size_t)(s * CN + (d0 + rc))) * HWN + pos] : 0.f;
        }
        __syncthreads();
        #pragma unroll 4
        for (int kk = 0; kk < COV_KC; ++kk) {
            float4 a = *reinterpret_cast<const float4*>(&Xc[kk][ty * 4]);
            float4 b = *reinterpret_cast<const float4*>(&Xd[kk][tx * 4]);
            float av[4] = {a.x, a.y, a.z, a.w};
            float bv[4] = {b.x, b.y, b.z, b.w};
            #pragma unroll
            for (int i = 0; i < 4; ++i)
                #pragma unroll
                for (int j = 0; j < 4; ++j)
                    acc[i][j] += av[i] * bv[j];
        }
        __syncthreads();
    }
    const float inv = 1.0f / (NSAMP - 1);
    #pragma unroll
    for (int i = 0; i < 4; ++i) {
        int c = c0 + ty * 4 + i;
        float mc = wmean[w * CN + c];
        #pragma unroll
        for (int j = 0; j < 4; ++j) {
            int d = d0 + tx * 4 + j;
            float md = wmean[w * CN + d];
            float val = (acc[i][j] - (float)NSAMP * mc * md) * inv;
            covb[((size_t)w * CN + c) * CN + d] = f2b(val);
        }
    }
}

// ---------------- scores init to conv_b ----------------
__global__ void init_scores(float* __restrict__ scores, const float* __restrict__ conv_b) {
    int i = blockIdx.x * blockDim.x + threadIdx.x;
    if (i < QN * WAYN) scores[i] = conv_b[0];
}

// ---------------- main: S = Abf @ Cov_w (128x512 per block), sim = rowdot(S, Abf), fused epilogue ----------------
// grid (600 m-tiles, 5 w), 256 thr (4 waves 2x2), 16x16x32 bf16 MFMA, BK=32, dbuf, swizzled LDS
__global__ __launch_bounds__(256, 2) void gemm_kernel(const u16* __restrict__ Abf,
                                                      const u16* __restrict__ covb,
                                                      const float* __restrict__ conv_w,
                                                      float* __restrict__ scores) {
    __shared__ __align__(16) u16 As[2][128 * 32];
    __shared__ __align__(16) u16 Bs[2][128 * 32];
    __shared__ float simlds[128][2];
    __shared__ float red[128];

    int r0 = blockIdx.x * 128;
    int w  = blockIdx.y;
    int q  = r0 >> 9;

    int t = threadIdx.x;
    int lane = t & 63, wid = t >> 6;
    int wr = wid >> 1, wc = wid & 1;
    int rl = lane & 15, g4 = lane >> 4;
    int swz = ((rl >> 1) & 3) << 4;     // read-side XOR (matches staging pre-swizzle)

    // staging per-lane constants: 2 loads per wave per tile
    int slot0 = wid * 2048 + lane * 16;             // + j*1024
    float simreg[16];
    #pragma unroll
    for (int i = 0; i < 16; ++i) simreg[i] = 0.f;

    const char* gAbase = (const char*)(Abf + (size_t)r0 * CN);          // row stride 1024 B
    const char* gBbase = (const char*)(covb + (size_t)w * CN * CN);     // row stride 1024 B

    for (int np = 0; np < 4; ++np) {
        int n0 = np * 128;
        f32x4 acc[4][4];
        #pragma unroll
        for (int mi = 0; mi < 4; ++mi)
            #pragma unroll
            for (int ni = 0; ni < 4; ++ni)
                acc[mi][ni] = (f32x4){0.f, 0.f, 0.f, 0.f};

        int buf = 0;
        // prologue stage ks=0
        #pragma unroll
        for (int j = 0; j < 2; ++j) {
            int slot = slot0 + j * 1024;
            int row = slot >> 6, kb = slot & 63;
            int kbs = kb ^ (((row >> 1) & 3) << 4);
            gload16(gAbase + (size_t)row * 1024 + kbs,
                    (char*)&As[0][0] + wid * 2048 + j * 1024);
            gload16(gBbase + (size_t)(n0 + row) * 1024 + kbs,
                    (char*)&Bs[0][0] + wid * 2048 + j * 1024);
        }
        __syncthreads();

        for (int ks = 0; ks < 16; ++ks) {
            if (ks < 15) {
                int koff = (ks + 1) * 64;   // bytes: 32 bf16
                #pragma unroll
                for (int j = 0; j < 2; ++j) {
                    int slot = slot0 + j * 1024;
                    int row = slot >> 6, kb = slot & 63;
                    int kbs = kb ^ (((row >> 1) & 3) << 4);
                    gload16(gAbase + (size_t)row * 1024 + koff + kbs,
                            (char*)&As[buf ^ 1][0] + wid * 2048 + j * 1024);
                    gload16(gBbase + (size_t)(n0 + row) * 1024 + koff + kbs,
                            (char*)&Bs[buf ^ 1][0] + wid * 2048 + j * 1024);
                }
            }
            const char* Ab = (const char*)&As[buf][0];
            const char* Bb = (const char*)&Bs[buf][0];
            short8 a[4], b[4];
            int kread = (g4 * 16) ^ swz;
            #pragma unroll
            for (int mi = 0; mi < 4; ++mi)
                a[mi] = *(const short8*)(Ab + (wr * 64 + mi * 16 + rl) * 64 + kread);
            #pragma unroll
            for (int ni = 0; ni < 4; ++ni)
                b[ni] = *(const short8*)(Bb + (wc * 64 + ni * 16 + rl) * 64 + kread);
            #pragma unroll
            for (int mi = 0; mi < 4; ++mi)
                #pragma unroll
                for (int ni = 0; ni < 4; ++ni)
                    acc[mi][ni] = __builtin_amdgcn_mfma_f32_16x16x32_bf16(
                        a[mi], b[ni], acc[mi][ni], 0, 0, 0);
            __syncthreads();
            buf ^= 1;
        }

        // epilogue: sim partial — multiply S by centered-q (re-read Abf) and accumulate
        #pragma unroll
        for (int mi = 0; mi < 4; ++mi) {
            #pragma unroll
            for (int r = 0; r < 4; ++r) {
                size_t row = (size_t)(r0 + wr * 64 + mi * 16 + g4 * 4 + r);
                float s = 0.f;
                #pragma unroll
                for (int ni = 0; ni < 4; ++ni) {
                    int d = n0 + wc * 64 + ni * 16 + rl;
                    s += acc[mi][ni][r] * b2f(Abf[row * CN + d]);
                }
                simreg[mi * 4 + r] += s;
            }
        }
    }

    // reduce sim over 16-lane col groups, combine wc halves, leaky+conv+score
    #pragma unroll
    for (int idx = 0; idx < 16; ++idx) {
        float v = simreg[idx];
        v += __shfl_xor(v, 1);
        v += __shfl_xor(v, 2);
        v += __shfl_xor(v, 4);
        v += __shfl_xor(v, 8);
        if (rl == 0)
            simlds[wr * 64 + (idx >> 2) * 16 + g4 * 4 + (idx & 3)][wc] = v;
    }
    __syncthreads();

    float contrib = 0.f;
    if (t < 128) {
        float sim = simlds[t][0] + simlds[t][1];
        int i = (r0 + t) & (MPAD - 1);
        float act = (sim >= 0.f) ? sim : 0.2f * sim;
        contrib = (i < HWN) ? act * conv_w[i] : 0.f;
        red[t] = contrib;
    }
    __syncthreads();
    if (t < 64) {
        float c = red[t] + red[t + 64];
        #pragma unroll
        for (int off = 32; off > 0; off >>= 1) c += __shfl_down(c, off);
        if (t == 0) atomicAdd(&scores[q * WAYN + w], c);
    }
}

extern "C" void kernel_launch(void* const* d_in, const int* in_sizes, int n_in,
                              void* d_out, int out_size, void* d_ws, size_t ws_size,
                              hipStream_t stream) {
    const float* x1     = (const float*)d_in[0];
    const float* x2     = (const float*)d_in[1];
    const float* conv_w = (const float*)d_in[2];
    const float* conv_b = (const float*)d_in[3];
    float* scores = (float*)d_out;

    char* ws = (char*)d_ws;
    u16* Abf    = (u16*)ws;                              // 76800*512*2 = 78,643,200 B
    u16* covb   = (u16*)(ws + 78643200);                 // 5*512*512*2 = 2,621,440 B
    float* wmean = (float*)(ws + 78643200 + 2621440);    // 10,240 B

    wmean_kernel<<<WAYN * CN, 64, 0, stream>>>(x2, wmean);
    qtrans_kernel<<<dim3(8, QN), 256, 0, stream>>>(x1, Abf);
    cov_kernel<<<dim3(8, 8, WAYN), dim3(16, 16), 0, stream>>>(x2, wmean, covb);
    init_scores<<<3, 256, 0, stream>>>(scores, conv_b);
    gemm_kernel<<<dim3(MTOT / 128, WAYN), 256, 0, stream>>>(Abf, covb, conv_w, scores);
}

// Round 4
// 403.634 us; speedup vs baseline: 6.3452x; 1.7639x over previous
//
#include <hip/hip_runtime.h>
#include <hip/hip_bf16.h>

#define QN 150
#define CN 512
#define HWN 441
#define WAYN 5
#define SHOTN 5
#define NSAMP 2205           // SHOT*HW
#define MROWS (QN * HWN)     // 66150 packed rows
#define MTILES 517           // ceil(66150/128)
#define MPADTOT (MTILES * 128)  // 66176
#define KP 2208              // cov K padded (32*69)
#define KPB (KP * 2)         // row bytes of x2c

typedef unsigned short u16;
typedef unsigned int u32;
typedef __attribute__((ext_vector_type(8))) short short8;
typedef __attribute__((ext_vector_type(4))) float f32x4;

__device__ __forceinline__ u16 f2b(float f) {
    return __builtin_bit_cast(u16, __float2bfloat16(f));
}
__device__ __forceinline__ float b2f(u16 h) {
    u32 u = ((u32)h) << 16;
    return __builtin_bit_cast(float, u);
}

__device__ __forceinline__ void gload16(const void* g, void* l) {
    __builtin_amdgcn_global_load_lds(
        (const __attribute__((address_space(1))) unsigned int*)g,
        (__attribute__((address_space(3))) unsigned int*)l, 16, 0, 0);
}

// ---------------- per-(way,channel) mean over 2205 samples ----------------
__global__ void wmean_kernel(const float* __restrict__ x2, float* __restrict__ wmean) {
    int wc = blockIdx.x;            // w*512 + c
    int w = wc >> 9, c = wc & 511;
    int lane = threadIdx.x;         // 64
    float s = 0.f;
    for (int sh = 0; sh < SHOTN; ++sh) {
        const float* p = x2 + ((size_t)((w * SHOTN + sh) * CN + c)) * HWN;
        for (int i = lane; i < HWN; i += 64) s += p[i];
    }
    #pragma unroll
    for (int off = 32; off > 0; off >>= 1) s += __shfl_down(s, off);
    if (lane == 0) wmean[wc] = s * (1.0f / NSAMP);
}

// ---------------- center x2 -> bf16 x2c[w][c][k], k = s*441+pos, pad [2205,2208)=0 ----------------
__global__ void x2center_kernel(const float* __restrict__ x2,
                                const float* __restrict__ wmean,
                                u16* __restrict__ x2c) {
    int b = blockIdx.x;             // ws*512 + c
    int ws = b >> 9, c = b & 511;
    int w = ws / SHOTN, s = ws - w * SHOTN;
    int lane = threadIdx.x;
    float m = wmean[w * CN + c];
    const float* src = x2 + (size_t)b * HWN;
    u16* dst = x2c + ((size_t)(w * CN + c)) * KP + s * HWN;
    for (int i = lane; i < HWN; i += 64) dst[i] = f2b(src[i] - m);
    if (s == 0 && lane < (KP - NSAMP))
        x2c[((size_t)(w * CN + c)) * KP + NSAMP + lane] = 0;
}

// ---------------- cov MFMA: covb[w] = Xc Xc^T / (n-1), 128x128 tile, K=2208 ----------------
__global__ __launch_bounds__(256, 2) void covmfma_kernel(const u16* __restrict__ x2c,
                                                         u16* __restrict__ covb) {
    __shared__ __align__(16) u16 As[2][128 * 32];
    __shared__ __align__(16) u16 Bs[2][128 * 32];
    int w  = blockIdx.z;
    int c0 = blockIdx.y * 128;
    int d0 = blockIdx.x * 128;
    int t = threadIdx.x;
    int lane = t & 63, wid = t >> 6;
    int wr = wid >> 1, wc = wid & 1;
    int rl = lane & 15, g4 = lane >> 4;
    int swz = ((rl >> 1) & 3) << 4;
    int s0 = wid * 2048 + lane * 16;

    const char* gX = (const char*)(x2c + (size_t)w * CN * KP);

    f32x4 acc[4][4];
    #pragma unroll
    for (int mi = 0; mi < 4; ++mi)
        #pragma unroll
        for (int ni = 0; ni < 4; ++ni)
            acc[mi][ni] = (f32x4){0.f, 0.f, 0.f, 0.f};

    int buf = 0;
    #pragma unroll
    for (int j = 0; j < 2; ++j) {
        int s = s0 + j * 1024;
        int row = s >> 6, kbs = (s & 63) ^ (((row >> 1) & 3) << 4);
        gload16(gX + (size_t)(c0 + row) * KPB + kbs, (char*)&As[0][0] + wid * 2048 + j * 1024);
        gload16(gX + (size_t)(d0 + row) * KPB + kbs, (char*)&Bs[0][0] + wid * 2048 + j * 1024);
    }
    __syncthreads();

    for (int ks = 0; ks < KP / 32; ++ks) {
        if (ks < KP / 32 - 1) {
            int koff = (ks + 1) * 64;
            #pragma unroll
            for (int j = 0; j < 2; ++j) {
                int s = s0 + j * 1024;
                int row = s >> 6, kbs = (s & 63) ^ (((row >> 1) & 3) << 4);
                gload16(gX + (size_t)(c0 + row) * KPB + koff + kbs,
                        (char*)&As[buf ^ 1][0] + wid * 2048 + j * 1024);
                gload16(gX + (size_t)(d0 + row) * KPB + koff + kbs,
                        (char*)&Bs[buf ^ 1][0] + wid * 2048 + j * 1024);
            }
        }
        const char* Ab = (const char*)&As[buf][0];
        const char* Bb = (const char*)&Bs[buf][0];
        int kread = (g4 * 16) ^ swz;
        short8 a[4], b[4];
        #pragma unroll
        for (int mi = 0; mi < 4; ++mi)
            a[mi] = *(const short8*)(Ab + (wr * 64 + mi * 16 + rl) * 64 + kread);
        #pragma unroll
        for (int ni = 0; ni < 4; ++ni)
            b[ni] = *(const short8*)(Bb + (wc * 64 + ni * 16 + rl) * 64 + kread);
        #pragma unroll
        for (int mi = 0; mi < 4; ++mi)
            #pragma unroll
            for (int ni = 0; ni < 4; ++ni)
                acc[mi][ni] = __builtin_amdgcn_mfma_f32_16x16x32_bf16(
                    a[mi], b[ni], acc[mi][ni], 0, 0, 0);
        __syncthreads();
        buf ^= 1;
    }

    const float inv = 1.0f / (NSAMP - 1);
    #pragma unroll
    for (int mi = 0; mi < 4; ++mi)
        #pragma unroll
        for (int r = 0; r < 4; ++r) {
            int c = c0 + wr * 64 + mi * 16 + g4 * 4 + r;
            #pragma unroll
            for (int ni = 0; ni < 4; ++ni) {
                int d = d0 + wc * 64 + ni * 16 + rl;
                covb[((size_t)w * CN + c) * CN + d] = f2b(acc[mi][ni][r] * inv);
            }
        }
}

// ---------------- transpose+center x1 -> Abf[(q*441+i)][c] bf16 (packed rows) ----------------
__global__ __launch_bounds__(256) void qtrans_kernel(const float* __restrict__ x1,
                                                     u16* __restrict__ Abf) {
    __shared__ u16 S[512][72];
    __shared__ float qm[64];
    int c0 = blockIdx.x * 64;
    int q  = blockIdx.y;
    int t = threadIdx.x;
    int lane = t & 63, cq = t >> 6;

    for (int cc = cq; cc < 64; cc += 4) {
        int c = c0 + cc;
        const float* p = x1 + ((size_t)q * CN + c) * HWN;
        float s = 0.f;
        for (int ic = 0; ic < 8; ++ic) {
            int i = ic * 64 + lane;
            float v = (i < HWN) ? p[i] : 0.f;
            s += v;
            S[i][cc] = f2b(v);
        }
        #pragma unroll
        for (int off = 32; off > 0; off >>= 1) s += __shfl_down(s, off);
        if (lane == 0) qm[cc] = s * (1.0f / HWN);
    }
    __syncthreads();

    int coct = t & 7;
    for (int p = 0; p < 16; ++p) {
        int il = p * 32 + (t >> 3);
        if (il >= HWN) continue;
        short8 v = *(const short8*)(&S[il][coct * 8]);
        short8 o;
        #pragma unroll
        for (int j = 0; j < 8; ++j) {
            float f = b2f((u16)v[j]) - qm[coct * 8 + j];
            o[j] = (short)f2b(f);
        }
        *(short8*)(Abf + ((size_t)(q * HWN + il)) * CN + c0 + coct * 8) = o;
    }
}

// ---------------- init: scores=conv_b, zero Abf pad rows ----------------
__global__ void init_misc(float* __restrict__ scores, const float* __restrict__ conv_b,
                          u32* __restrict__ AbfPad32) {
    int t = threadIdx.x;
    for (int i = t; i < QN * WAYN; i += 256) scores[i] = conv_b[0];
    int padwords = (MPADTOT - MROWS) * CN / 2;   // 26*512/2 = 6656
    for (int i = t; i < padwords; i += 256) AbfPad32[i] = 0;
}

// ---------------- main: S = Abf @ Cov_w (128x512, BN=256 x 2 passes), fused sim epilogue ----------------
__global__ __launch_bounds__(256, 2) void gemm_kernel(const u16* __restrict__ Abf,
                                                      const u16* __restrict__ covb,
                                                      const float* __restrict__ conv_w,
                                                      float* __restrict__ scores) {
    __shared__ __align__(16) u16 As[2][128 * 32];
    __shared__ __align__(16) u16 Bs[2][256 * 32];
    __shared__ float simlds[128][2];
    __shared__ float redlo[128];
    __shared__ float redhi[128];

    int r0 = blockIdx.x * 128;
    int w  = blockIdx.y;
    int t = threadIdx.x;
    int lane = t & 63, wid = t >> 6;
    int wr = wid >> 1, wc = wid & 1;
    int rl = lane & 15, g4 = lane >> 4;
    int swz = ((rl >> 1) & 3) << 4;

    int sA0 = wid * 2048 + lane * 16;
    int sB0 = wid * 4096 + lane * 16;

    float simreg[16];
    #pragma unroll
    for (int i = 0; i < 16; ++i) simreg[i] = 0.f;

    const char* gA = (const char*)(Abf + (size_t)r0 * CN);
    const char* gB = (const char*)(covb + (size_t)w * CN * CN);

    for (int np = 0; np < 2; ++np) {
        int n0 = np * 256;
        f32x4 acc[4][8];
        #pragma unroll
        for (int mi = 0; mi < 4; ++mi)
            #pragma unroll
            for (int ni = 0; ni < 8; ++ni)
                acc[mi][ni] = (f32x4){0.f, 0.f, 0.f, 0.f};

        int buf = 0;
        #pragma unroll
        for (int j = 0; j < 2; ++j) {
            int s = sA0 + j * 1024;
            int row = s >> 6, kbs = (s & 63) ^ (((row >> 1) & 3) << 4);
            gload16(gA + (size_t)row * 1024 + kbs, (char*)&As[0][0] + wid * 2048 + j * 1024);
        }
        #pragma unroll
        for (int j = 0; j < 4; ++j) {
            int s = sB0 + j * 1024;
            int row = s >> 6, kbs = (s & 63) ^ (((row >> 1) & 3) << 4);
            gload16(gB + (size_t)(n0 + row) * 1024 + kbs, (char*)&Bs[0][0] + wid * 4096 + j * 1024);
        }
        __syncthreads();

        for (int ks = 0; ks < 16; ++ks) {
            if (ks < 15) {
                int koff = (ks + 1) * 64;
                #pragma unroll
                for (int j = 0; j < 2; ++j) {
                    int s = sA0 + j * 1024;
                    int row = s >> 6, kbs = (s & 63) ^ (((row >> 1) & 3) << 4);
                    gload16(gA + (size_t)row * 1024 + koff + kbs,
                            (char*)&As[buf ^ 1][0] + wid * 2048 + j * 1024);
                }
                #pragma unroll
                for (int j = 0; j < 4; ++j) {
                    int s = sB0 + j * 1024;
                    int row = s >> 6, kbs = (s & 63) ^ (((row >> 1) & 3) << 4);
                    gload16(gB + (size_t)(n0 + row) * 1024 + koff + kbs,
                            (char*)&Bs[buf ^ 1][0] + wid * 4096 + j * 1024);
                }
            }
            const char* Ab = (const char*)&As[buf][0];
            const char* Bb = (const char*)&Bs[buf][0];
            int kread = (g4 * 16) ^ swz;
            short8 a[4], b[8];
            #pragma unroll
            for (int mi = 0; mi < 4; ++mi)
                a[mi] = *(const short8*)(Ab + (wr * 64 + mi * 16 + rl) * 64 + kread);
            #pragma unroll
            for (int ni = 0; ni < 8; ++ni)
                b[ni] = *(const short8*)(Bb + (wc * 128 + ni * 16 + rl) * 64 + kread);
            #pragma unroll
            for (int mi = 0; mi < 4; ++mi)
                #pragma unroll
                for (int ni = 0; ni < 8; ++ni)
                    acc[mi][ni] = __builtin_amdgcn_mfma_f32_16x16x32_bf16(
                        a[mi], b[ni], acc[mi][ni], 0, 0, 0);
            __syncthreads();
            buf ^= 1;
        }

        // sim partials: rowdot(S, Qc) over this np's 256 d's
        #pragma unroll
        for (int mi = 0; mi < 4; ++mi)
            #pragma unroll
            for (int r = 0; r < 4; ++r) {
                size_t row = (size_t)(r0 + wr * 64 + mi * 16 + g4 * 4 + r);
                float s = 0.f;
                #pragma unroll
                for (int ni = 0; ni < 8; ++ni) {
                    int d = n0 + wc * 128 + ni * 16 + rl;
                    s += acc[mi][ni][r] * b2f(Abf[row * CN + d]);
                }
                simreg[mi * 4 + r] += s;
            }
    }

    #pragma unroll
    for (int idx = 0; idx < 16; ++idx) {
        float v = simreg[idx];
        v += __shfl_xor(v, 1);
        v += __shfl_xor(v, 2);
        v += __shfl_xor(v, 4);
        v += __shfl_xor(v, 8);
        if (rl == 0)
            simlds[wr * 64 + (idx >> 2) * 16 + g4 * 4 + (idx & 3)][wc] = v;
    }
    __syncthreads();

    int qlo = r0 / HWN;
    if (t < 128) {
        float sim = simlds[t][0] + simlds[t][1];
        int r = r0 + t;
        int q = r / HWN;
        int i = r - q * HWN;
        float act = (sim >= 0.f) ? sim : 0.2f * sim;
        float contrib = (r < MROWS) ? act * conv_w[i] : 0.f;
        redlo[t] = (q == qlo) ? contrib : 0.f;
        redhi[t] = (q == qlo) ? 0.f : contrib;
    }
    __syncthreads();
    if (t < 64) {
        float cl = redlo[t] + redlo[t + 64];
        float ch = redhi[t] + redhi[t + 64];
        #pragma unroll
        for (int off = 32; off > 0; off >>= 1) {
            cl += __shfl_down(cl, off);
            ch += __shfl_down(ch, off);
        }
        if (t == 0) {
            atomicAdd(&scores[qlo * WAYN + w], cl);
            if (qlo + 1 < QN) atomicAdd(&scores[(qlo + 1) * WAYN + w], ch);
        }
    }
}

extern "C" void kernel_launch(void* const* d_in, const int* in_sizes, int n_in,
                              void* d_out, int out_size, void* d_ws, size_t ws_size,
                              hipStream_t stream) {
    const float* x1     = (const float*)d_in[0];
    const float* x2     = (const float*)d_in[1];
    const float* conv_w = (const float*)d_in[2];
    const float* conv_b = (const float*)d_in[3];
    float* scores = (float*)d_out;

    char* ws = (char*)d_ws;
    u16* covb    = (u16*)ws;                               // 5*512*512*2 = 2,621,440 B
    float* wmean = (float*)(ws + 2621440);                 // 10,240 B
    // x2c aliases the head of Abf: covmfma (reads x2c) completes before qtrans (writes Abf)
    u16* x2c     = (u16*)(ws + 2631680);                   // 5*512*2208*2 = 11,304,960 B
    u16* Abf     = (u16*)(ws + 2631680);                   // 66176*512*2 = 67,764,224 B

    wmean_kernel<<<WAYN * CN, 64, 0, stream>>>(x2, wmean);
    x2center_kernel<<<WAYN * SHOTN * CN, 64, 0, stream>>>(x2, wmean, x2c);
    covmfma_kernel<<<dim3(4, 4, WAYN), 256, 0, stream>>>(x2c, covb);
    qtrans_kernel<<<dim3(8, QN), 256, 0, stream>>>(x1, Abf);
    init_misc<<<1, 256, 0, stream>>>(scores, conv_b, (u32*)(Abf + (size_t)MROWS * CN));
    gemm_kernel<<<dim3(MTILES, WAYN), 256, 0, stream>>>(Abf, covb, conv_w, scores);
}